// Round 5
// baseline (129.372 us; speedup 1.0000x reference)
//
#include <hip/hip_runtime.h>

#define NB   2
#define SKV  1024
#define NSQ  512
#define HIN  256
#define HA   128
#define NQ   (NB * NSQ)      // 1024 total q rows
#define NR   (NB * SKV)      // 2048 total kv rows

// proj stores E = exp2(KSC*p) = e^{2p};  tanh(pk+pq) = 1 - 2/(Ek*Eq+1)
// score' = -2*sum_a wv_a/(Ek*Eq+1)   (W0+bv constants cancel in softmax)
#define KSC 2.8853900817779268f      // 2*log2(e)

typedef float v2f __attribute__((ext_vector_type(2)));
__device__ __forceinline__ v2f pkfma(v2f a, v2f b, v2f c) {
    return __builtin_elementwise_fma(a, b, c);
}

// ---------------- K1: projections -> E, with ek TRANSPOSED ----------------
// blocks 0..255: kv rows (8/block) -> ekT[a][row]; 256..383: q rows -> eq[q][a]
__global__ __launch_bounds__(256) void proj_kernel(
    const float* __restrict__ kv,  const float* __restrict__ qy,
    const float* __restrict__ Wkv, const float* __restrict__ bkv,
    const float* __restrict__ Wq,  const float* __restrict__ bq,
    float* __restrict__ ekT,       // [HA][NR]
    float* __restrict__ eq)        // [NQ][HA]
{
    const int t = threadIdx.x;
    const int a = t & 127;                                   // channel
    const int g = __builtin_amdgcn_readfirstlane(t >> 7);    // 0/1, wave-uniform
    const int blk = blockIdx.x;
    const bool is_q = blk >= 256;
    const int r0 = (is_q ? (blk - 256) : blk) * 8 + g * 4;   // row base in tensor
    const float* __restrict__ src = (is_q ? qy : kv) + (size_t)r0 * HIN; // uniform
    const float* __restrict__ W  = is_q ? Wq : Wkv;
    const float* __restrict__ bs = is_q ? bq : bkv;

    float ac0 = 0.f, ac1 = 0.f, ac2 = 0.f, ac3 = 0.f;
    #pragma unroll 8
    for (int h = 0; h < HIN; ++h) {
        const float w  = W[(size_t)h * HA + a];   // coalesced dword, L1-hot
        const float x0 = src[h];                  // uniform -> s_load
        const float x1 = src[HIN + h];
        const float x2 = src[2 * HIN + h];
        const float x3 = src[3 * HIN + h];
        ac0 = fmaf(x0, w, ac0);
        ac1 = fmaf(x1, w, ac1);
        ac2 = fmaf(x2, w, ac2);
        ac3 = fmaf(x3, w, ac3);
    }
    const float bb = bs[a];
    const float o0 = __builtin_amdgcn_exp2f((ac0 + bb) * KSC);
    const float o1 = __builtin_amdgcn_exp2f((ac1 + bb) * KSC);
    const float o2 = __builtin_amdgcn_exp2f((ac2 + bb) * KSC);
    const float o3 = __builtin_amdgcn_exp2f((ac3 + bb) * KSC);
    if (!is_q) {
        float* __restrict__ d = ekT + (size_t)a * NR + r0;   // scatter (stores don't stall)
        d[0] = o0; d[1] = o1; d[2] = o2; d[3] = o3;
    } else {
        eq[(size_t)(r0 + 0) * HA + a] = o0;                  // coalesced
        eq[(size_t)(r0 + 1) * HA + a] = o1;
        eq[(size_t)(r0 + 2) * HA + a] = o2;
        eq[(size_t)(r0 + 3) * HA + a] = o3;
    }
}

// ---------------- K2: scores + exp (unnormalized), SGPR-fed ----------------
// block = (q-oct, s-quarter); 256 thr; grid 512
__global__ __launch_bounds__(256) void score_kernel(
    const float* __restrict__ ekT,  // [HA][NR]
    const float* __restrict__ eq,   // [NQ][HA]
    const float* __restrict__ wv,   // [HA]
    float* __restrict__ ew,         // [NQ][SKV] unnormalized exp(score)
    float* __restrict__ ewT,        // [NQ/8][SKV][8]
    float* __restrict__ Dp)         // [4][NQ] partial denominators
{
    __shared__ float dred[4][8];
    const int t = threadIdx.x;
    const int lane = t & 63, wid = t >> 6;
    const int blk = blockIdx.x;        // 0..511
    const int sq  = blk & 3;
    const int oct = blk >> 2;          // 0..127
    const int q0  = oct * 8;
    const int b   = q0 >> 9;
    const int s   = sq * 256 + t;      // kv index within b
    const int srow = b * SKV + s;

    v2f acc[8];
    #pragma unroll
    for (int j = 0; j < 8; ++j) acc[j] = (v2f){0.f, 0.f};
    const v2f one = {1.f, 1.f};

    #pragma unroll 2
    for (int a4 = 0; a4 < 32; ++a4) {
        const float E0 = ekT[(size_t)(a4 * 4 + 0) * NR + srow];  // coalesced dword
        const float E1 = ekT[(size_t)(a4 * 4 + 1) * NR + srow];
        const float E2 = ekT[(size_t)(a4 * 4 + 2) * NR + srow];
        const float E3 = ekT[(size_t)(a4 * 4 + 3) * NR + srow];
        const float4 w4 = *(const float4*)(wv + a4 * 4);         // uniform -> s_load
        const v2f E01 = {E0, E1}, E23 = {E2, E3};
        const v2f w01 = {w4.x, w4.y}, w23 = {w4.z, w4.w};
        #pragma unroll
        for (int j = 0; j < 8; ++j) {
            const float4 qv = *(const float4*)(eq + (size_t)(q0 + j) * HA + a4 * 4); // s_load
            const v2f A = pkfma(E01, (v2f){qv.x, qv.y}, one);
            const v2f B = pkfma(E23, (v2f){qv.z, qv.w}, one);
            const v2f m = A * B;
            const float r = __builtin_amdgcn_rcpf(m.x * m.y);
            const v2f ts = (v2f){m.y, m.x} * (v2f){r, r};        // (1/m.x, 1/m.y)
            acc[j] = pkfma(w01, ts * B, acc[j]);                 // w01/A
            acc[j] = pkfma(w23, ts * A, acc[j]);                 // w23/B
        }
    }

    float ev[8];
    #pragma unroll
    for (int j = 0; j < 8; ++j) {
        ev[j] = __builtin_amdgcn_exp2f(-KSC * (acc[j].x + acc[j].y)); // = e^{score}
        ew[(size_t)(q0 + j) * SKV + s] = ev[j];                  // coalesced
    }
    {   // transposed copy for K3's s_load path: 8 contiguous floats per (oct,s)
        float* __restrict__ wp = ewT + ((size_t)oct * SKV + s) * 8;
        *(float4*)(wp)     = make_float4(ev[0], ev[1], ev[2], ev[3]);
        *(float4*)(wp + 4) = make_float4(ev[4], ev[5], ev[6], ev[7]);
    }
    #pragma unroll
    for (int j = 0; j < 8; ++j) {
        float ss = ev[j];
        #pragma unroll
        for (int o = 32; o > 0; o >>= 1) ss += __shfl_down(ss, o);
        if (lane == 0) dred[wid][j] = ss;
    }
    __syncthreads();
    if (t < 8) {
        float d = dred[0][t] + dred[1][t] + dred[2][t] + dred[3][t];
        Dp[(size_t)sq * NQ + q0 + t] = d;
    }
}

// ---------------- K3: output GEMM partials (no LDS, no sync) ----------------
// block = (q16 group, s-quarter); 512 thr; wave <-> s-subchunk; lane <-> h-quad
__global__ __launch_bounds__(512) void out_kernel(
    const float* __restrict__ ewT,  // [NQ/8][SKV][8]
    const float* __restrict__ kv,   // [NR][HIN]
    float* __restrict__ P)          // [32][NQ*HIN] unnormalized partials
{
    const int t = threadIdx.x;
    const int lane = t & 63;
    const int wu = __builtin_amdgcn_readfirstlane(t >> 6);   // 0..7, wave-uniform
    const int blk = blockIdx.x;        // 0..255
    const int k  = blk & 3;            // s-quarter
    const int gi = blk >> 2;           // 0..63
    const int q0 = gi * 16;
    const int b  = q0 >> 9;
    const int o0 = q0 >> 3;            // first oct

    v2f acc[16][2];
    #pragma unroll
    for (int j = 0; j < 16; ++j) { acc[j][0] = (v2f){0.f, 0.f}; acc[j][1] = (v2f){0.f, 0.f}; }

    const int sbase = k * 256 + wu * 32;                     // wave-uniform
    const float* __restrict__ kvb = kv + ((size_t)b * SKV + sbase) * HIN + lane * 4;
    const float* __restrict__ wA = ewT + ((size_t)o0 * SKV + sbase) * 8;       // uniform
    const float* __restrict__ wB = ewT + ((size_t)(o0 + 1) * SKV + sbase) * 8; // uniform

    #pragma unroll 4
    for (int i = 0; i < 32; ++i) {
        const float4 v = *(const float4*)(kvb + (size_t)i * HIN);  // coalesced 1KB
        const v2f vlo = {v.x, v.y}, vhi = {v.z, v.w};
        const float4 a0 = *(const float4*)(wA + (size_t)i * 8);    // s_load
        const float4 a1 = *(const float4*)(wA + (size_t)i * 8 + 4);
        const float4 b0 = *(const float4*)(wB + (size_t)i * 8);
        const float4 b1 = *(const float4*)(wB + (size_t)i * 8 + 4);
        const float wq[16] = {a0.x, a0.y, a0.z, a0.w, a1.x, a1.y, a1.z, a1.w,
                              b0.x, b0.y, b0.z, b0.w, b1.x, b1.y, b1.z, b1.w};
        #pragma unroll
        for (int j = 0; j < 16; ++j) {
            const v2f wj = {wq[j], wq[j]};
            acc[j][0] = pkfma(vlo, wj, acc[j][0]);
            acc[j][1] = pkfma(vhi, wj, acc[j][1]);
        }
    }
    float* __restrict__ Pp = P + (size_t)(k * 8 + wu) * ((size_t)NQ * HIN);
    #pragma unroll
    for (int j = 0; j < 16; ++j) {
        *(float4*)(Pp + (size_t)(q0 + j) * HIN + lane * 4) =
            make_float4(acc[j][0].x, acc[j][0].y, acc[j][1].x, acc[j][1].y);
    }
}

// ---------------- K4: normalize weights + reduce partials ----------------
__global__ __launch_bounds__(256) void final_kernel(
    const float* __restrict__ ew,   // [NQ][SKV]
    const float* __restrict__ Dp,   // [4][NQ]
    const float* __restrict__ P,    // [32][NQ*HIN]
    float* __restrict__ out)        // [262144 out0][1048576 weights]
{
    const int t = threadIdx.x;
    const int q = blockIdx.x;       // 0..1023
    const float D = Dp[q] + Dp[NQ + q] + Dp[2 * NQ + q] + Dp[3 * NQ + q]; // s_load
    const float rw = 1.0f / D;

    float* __restrict__ outw = out + (size_t)NQ * HIN;
    #pragma unroll
    for (int c = 0; c < 4; ++c) {
        const int s = c * 256 + t;
        outw[(size_t)q * SKV + s] = ew[(size_t)q * SKV + s] * rw;  // coalesced
    }
    float v = 0.f;
    #pragma unroll
    for (int p = 0; p < 32; ++p)
        v += P[(size_t)p * ((size_t)NQ * HIN) + (size_t)q * HIN + t];  // coalesced
    out[(size_t)q * HIN + t] = v * rw;
}

extern "C" void kernel_launch(void* const* d_in, const int* in_sizes, int n_in,
                              void* d_out, int out_size, void* d_ws, size_t ws_size,
                              hipStream_t stream) {
    (void)in_sizes; (void)n_in; (void)out_size; (void)ws_size;
    const float* kv  = (const float*)d_in[0];
    const float* qy  = (const float*)d_in[1];
    const float* Wkv = (const float*)d_in[2];
    const float* bkv = (const float*)d_in[3];
    const float* Wq  = (const float*)d_in[4];
    const float* bq  = (const float*)d_in[5];
    const float* wv  = (const float*)d_in[6];
    const float* bv  = (const float*)d_in[7];
    (void)bv;  // constant shift — cancels in softmax

    float* ekT = (float*)d_ws;              // 262144 f  (1 MB)
    float* eq  = ekT + 262144;              // 131072 f
    float* ew  = eq  + 131072;              // 1048576 f (4 MB)
    float* ewT = ew  + 1048576;             // 1048576 f (4 MB)
    float* Dp  = ewT + 1048576;             // 4096 f
    float* P   = Dp  + 4096;                // 8388608 f (32 MB)
    float* out = (float*)d_out;

    hipLaunchKernelGGL(proj_kernel,  dim3(384),  dim3(256), 0, stream,
                       kv, qy, Wkv, bkv, Wq, bq, ekT, eq);
    hipLaunchKernelGGL(score_kernel, dim3(512),  dim3(256), 0, stream,
                       ekT, eq, wv, ew, ewT, Dp);
    hipLaunchKernelGGL(out_kernel,   dim3(256),  dim3(512), 0, stream,
                       ewT, kv, P);
    hipLaunchKernelGGL(final_kernel, dim3(1024), dim3(256), 0, stream,
                       ew, Dp, P, out);
}